// Round 6
// baseline (464.492 us; speedup 1.0000x reference)
//
#include <hip/hip_runtime.h>

// x[T=4,B=32,N=1024,C=256] -> Linear -> BN -> LIF -> Linear -> BN -> LIF
// M = 131072 rows, fp32 in/out. Spikes are 0/1 (exact in bf16) -> GEMM2 via
// exact 3-term bf16 split of W2 on matrix cores.
// Round 6: gemm2 occupancy fix — bb[2][4] per-t prefetch (~126 VGPR) +
// __launch_bounds__(512,4) -> 2 blocks/CU, 4 waves/SIMD.

typedef __attribute__((ext_vector_type(8))) short bf16x8;
typedef __attribute__((ext_vector_type(4))) float f32x4;

__device__ __forceinline__ unsigned short f32_to_bf16_rne(float f) {
    unsigned int u = __builtin_bit_cast(unsigned int, f);
    u += 0x7FFFu + ((u >> 16) & 1u);
    return (unsigned short)(u >> 16);
}
__device__ __forceinline__ float bf16_to_f32(unsigned short h) {
    unsigned int u = ((unsigned int)h) << 16;
    return __builtin_bit_cast(float, u);
}

// ---------------- GEMM1: C[M,256] = A[M,256] @ B[256,256] + bias (fp32 VALU) --------
// + fused per-channel column stats (fp64, deterministic fixed order).
__global__ __launch_bounds__(256) void sgemm256(const float* __restrict__ A,
                                                const float* __restrict__ B,
                                                const float* __restrict__ bias,
                                                float* __restrict__ C,
                                                double* __restrict__ partial) {
    __shared__ __align__(16) char smem[16640];
    float (*As)[132] = (float (*)[132])smem;            // 16x132 fp32 = 8448 B
    float (*Bs)[128] = (float (*)[128])(smem + 8448);   // 16x128 fp32 = 8192 B
    const int bj = blockIdx.x & 1;
    const int bi = blockIdx.x >> 1;
    const int tid = threadIdx.x;
    const int tx = tid & 15, ty = tid >> 4;
    const size_t m0 = (size_t)bi * 128;
    const int n0 = bj * 128;

    const int arow = tid >> 2, acol = (tid & 3) << 2;
    const int brow = tid >> 5, bcol = (tid & 31) << 2;

    float acc[8][8];
#pragma unroll
    for (int i = 0; i < 8; ++i)
#pragma unroll
        for (int j = 0; j < 8; ++j) acc[i][j] = 0.0f;

    for (int k0 = 0; k0 < 256; k0 += 16) {
        float4 a0 = *(const float4*)(A + (m0 + arow) * 256 + k0 + acol);
        float4 a1 = *(const float4*)(A + (m0 + arow + 64) * 256 + k0 + acol);
        float4 b0 = *(const float4*)(B + (size_t)(k0 + brow) * 256 + n0 + bcol);
        float4 b1 = *(const float4*)(B + (size_t)(k0 + brow + 8) * 256 + n0 + bcol);
        __syncthreads();
        As[acol + 0][arow] = a0.x;
        As[acol + 1][arow] = a0.y;
        As[acol + 2][arow] = a0.z;
        As[acol + 3][arow] = a0.w;
        As[acol + 0][arow + 64] = a1.x;
        As[acol + 1][arow + 64] = a1.y;
        As[acol + 2][arow + 64] = a1.z;
        As[acol + 3][arow + 64] = a1.w;
        *(float4*)&Bs[brow][bcol] = b0;
        *(float4*)&Bs[brow + 8][bcol] = b1;
        __syncthreads();
#pragma unroll
        for (int kk = 0; kk < 16; ++kk) {
            float4 av0 = *(const float4*)&As[kk][ty * 8];
            float4 av1 = *(const float4*)&As[kk][ty * 8 + 4];
            float4 bv0 = *(const float4*)&Bs[kk][tx * 4];
            float4 bv1 = *(const float4*)&Bs[kk][64 + tx * 4];
            float a[8] = {av0.x, av0.y, av0.z, av0.w, av1.x, av1.y, av1.z, av1.w};
            float b[8] = {bv0.x, bv0.y, bv0.z, bv0.w, bv1.x, bv1.y, bv1.z, bv1.w};
#pragma unroll
            for (int i = 0; i < 8; ++i)
#pragma unroll
                for (int j = 0; j < 8; ++j) acc[i][j] += a[i] * b[j];
        }
    }

    float bv[8];
#pragma unroll
    for (int j = 0; j < 4; ++j) bv[j] = bias[n0 + tx * 4 + j];
#pragma unroll
    for (int j = 4; j < 8; ++j) bv[j] = bias[n0 + 64 + tx * 4 + (j - 4)];
#pragma unroll
    for (int i = 0; i < 8; ++i) {
        size_t row = m0 + (size_t)(ty * 8 + i);
        float4 o0 = make_float4(acc[i][0] + bv[0], acc[i][1] + bv[1],
                                acc[i][2] + bv[2], acc[i][3] + bv[3]);
        float4 o1 = make_float4(acc[i][4] + bv[4], acc[i][5] + bv[5],
                                acc[i][6] + bv[6], acc[i][7] + bv[7]);
        *(float4*)(C + row * 256 + n0 + tx * 4) = o0;
        *(float4*)(C + row * 256 + n0 + 64 + tx * 4) = o1;
    }

    // ---- fused column stats (reuse smem as two 16x64 f64 arrays) ----
    __syncthreads();
    double (*redS)[64] = (double (*)[64])smem;          // 8 KB
    double (*redQ)[64] = (double (*)[64])(smem + 8192); // 8 KB
    {
        double sj[4] = {0, 0, 0, 0}, qj[4] = {0, 0, 0, 0};
#pragma unroll
        for (int i = 0; i < 8; ++i)
#pragma unroll
            for (int j = 0; j < 4; ++j) {
                float hv = acc[i][j] + bv[j];
                sj[j] += (double)hv;
                qj[j] += (double)hv * (double)hv;
            }
#pragma unroll
        for (int j = 0; j < 4; ++j) {
            redS[ty][4 * tx + j] = sj[j];
            redQ[ty][4 * tx + j] = qj[j];
        }
    }
    __syncthreads();
    if (tid < 64) {
        double ssum = 0.0, qsum = 0.0;
#pragma unroll
        for (int r = 0; r < 16; ++r) { ssum += redS[r][tid]; qsum += redQ[r][tid]; }
        int c = n0 + tid;
        partial[(size_t)c * 1024 + bi] = ssum;
        partial[(size_t)(256 + c) * 1024 + bi] = qsum;
    }
    __syncthreads();
    {
        double sj[4] = {0, 0, 0, 0}, qj[4] = {0, 0, 0, 0};
#pragma unroll
        for (int i = 0; i < 8; ++i)
#pragma unroll
            for (int j = 0; j < 4; ++j) {
                float hv = acc[i][4 + j] + bv[4 + j];
                sj[j] += (double)hv;
                qj[j] += (double)hv * (double)hv;
            }
#pragma unroll
        for (int j = 0; j < 4; ++j) {
            redS[ty][4 * tx + j] = sj[j];
            redQ[ty][4 * tx + j] = qj[j];
        }
    }
    __syncthreads();
    if (tid < 64) {
        double ssum = 0.0, qsum = 0.0;
#pragma unroll
        for (int r = 0; r < 16; ++r) { ssum += redS[r][tid]; qsum += redQ[r][tid]; }
        int c = n0 + 64 + tid;
        partial[(size_t)c * 1024 + bi] = ssum;
        partial[(size_t)(256 + c) * 1024 + bi] = qsum;
    }
}

// -------- W2 split: W2[k][n] fp32 -> W2catT[t][n][k] bf16, t=hi/mid/lo (exact sum) ----
__global__ __launch_bounds__(256) void split_w2(const float* __restrict__ W2,
                                                unsigned short* __restrict__ Bt) {
    int i = blockIdx.x * 256 + threadIdx.x;  // 65536
    int k = i >> 8, n = i & 255;
    float w = W2[i];
    unsigned short hi = f32_to_bf16_rne(w);
    float r = w - bf16_to_f32(hi);
    unsigned short mid = f32_to_bf16_rne(r);
    float r2 = r - bf16_to_f32(mid);
    unsigned short lo = f32_to_bf16_rne(r2);
    Bt[(size_t)(0 * 256 + n) * 256 + k] = hi;
    Bt[(size_t)(1 * 256 + n) * 256 + k] = mid;
    Bt[(size_t)(2 * 256 + n) * 256 + k] = lo;
}

// ---------------- GEMM2 v4 (MFMA): C = spikes_bf16 @ (Whi+Wmid+Wlo) + bias -----------
// 512 thr / 8 waves; A tile (128x256 bf16, 64KB) staged once, XOR-swizzled; barrier-
// free K-loop. bb[2][4]: prefetch per-t step (distance 16 MFMA) -> ~126 VGPR so
// 2 blocks/CU (4 waves/SIMD) co-reside. Fused column stats in epilogue.
__global__ __launch_bounds__(512, 4) void gemm2_mfma(const unsigned short* __restrict__ A,
                                                     const unsigned short* __restrict__ Bt,
                                                     const float* __restrict__ bias,
                                                     float* __restrict__ C,
                                                     double* __restrict__ partial) {
    __shared__ __align__(16) unsigned short Asw[128 * 256];  // 64 KB
    const size_t m0 = (size_t)blockIdx.x * 128;
    const int tid = threadIdx.x;
    const int lane = tid & 63;
    const int wave = tid >> 6;   // 0..7
    const int wr = wave >> 2;    // 0..1
    const int wc = wave & 3;     // 0..3
    const int lrow = lane & 15, lchunk = lane >> 4;

    const unsigned short* Bbase =
        Bt + ((size_t)(64 * wc + lrow)) * 256 + lchunk * 8;

    bf16x8 bb[2][4];
#define LOADB(buf, tt, kk)                                                    \
    _Pragma("unroll") for (int nf = 0; nf < 4; ++nf)                          \
        bb[buf][nf] = *(const bf16x8*)(Bbase + (size_t)(tt) * 65536 +         \
                                       nf * 4096 + (kk) * 32);

    LOADB(0, 0, 0)  // in flight during staging

    // ---- stage contiguous 64KB A tile; linear global reads, swizzled LDS writes ----
    {
        const char* src = (const char*)(A + m0 * 256);
        char* dst = (char*)Asw;
#pragma unroll
        for (int it = 0; it < 8; ++it) {
            unsigned off = (unsigned)(it * 512 + tid) * 16u;
            float4 v = *(const float4*)(src + off);
            unsigned swz = off ^ (((off >> 9) & 7u) << 4);
            *(float4*)(dst + swz) = v;
        }
    }
    __syncthreads();

    f32x4 acc[4][4] = {};

#pragma unroll
    for (int k0 = 0; k0 < 8; ++k0) {
        bf16x8 af[4];
#pragma unroll
        for (int mf = 0; mf < 4; ++mf) {
            unsigned r = (unsigned)(64 * wr + 16 * mf + lrow);
            unsigned off = r * 512u + (unsigned)(k0 * 64 + lchunk * 16);
            off ^= ((r & 7u) << 4);
            af[mf] = *(const bf16x8*)((const char*)Asw + off);
        }
#pragma unroll
        for (int t = 0; t < 3; ++t) {
            const int s = k0 * 3 + t;
            const int cur = s & 1;
            if (s < 23) { LOADB(cur ^ 1, ((s + 1) % 3), ((s + 1) / 3)) }
#pragma unroll
            for (int nf = 0; nf < 4; ++nf)
#pragma unroll
                for (int mf = 0; mf < 4; ++mf)
                    acc[mf][nf] = __builtin_amdgcn_mfma_f32_16x16x32_bf16(
                        af[mf], bb[cur][nf], acc[mf][nf], 0, 0, 0);
        }
    }
#undef LOADB

    // ---- C write + lane-local fp64 column sums ----
    double s[4], q[4];
#pragma unroll
    for (int nf = 0; nf < 4; ++nf) {
        int col = 64 * wc + 16 * nf + lrow;
        float bvv = bias[col];
        double ss = 0.0, qq = 0.0;
#pragma unroll
        for (int mf = 0; mf < 4; ++mf) {
            size_t rowb = m0 + 64 * wr + 16 * mf + 4 * lchunk;
#pragma unroll
            for (int e = 0; e < 4; ++e) {
                float hv = acc[mf][nf][e] + bvv;
                C[(rowb + e) * 256 + col] = hv;
                ss += (double)hv;
                qq += (double)hv * (double)hv;
            }
        }
        s[nf] = ss;
        q[nf] = qq;
    }
    // butterfly over lchunk (lane bits 4,5): fixed order, deterministic
#pragma unroll
    for (int nf = 0; nf < 4; ++nf) {
        s[nf] += __shfl_xor(s[nf], 16);
        s[nf] += __shfl_xor(s[nf], 32);
        q[nf] += __shfl_xor(q[nf], 16);
        q[nf] += __shfl_xor(q[nf], 32);
    }
    __syncthreads();                 // all waves done with Asw
    double* shred = (double*)Asw;    // 8 KB reuse: [wave][nf][lrow] (+512 for sq)
    if (lane < 16) {
#pragma unroll
        for (int nf = 0; nf < 4; ++nf) {
            shred[(wave * 4 + nf) * 16 + lane] = s[nf];
            shred[512 + (wave * 4 + nf) * 16 + lane] = q[nf];
        }
    }
    __syncthreads();
    if (wave < 4) {  // wave = wc slot; lanes 0..63 -> (nf, lrow)
        int nf = lane >> 4, lr = lane & 15;
        int col = 64 * wave + 16 * nf + lr;
        double ssum = shred[(wave * 4 + nf) * 16 + lr] +
                      shred[((4 + wave) * 4 + nf) * 16 + lr];
        double qsum = shred[512 + (wave * 4 + nf) * 16 + lr] +
                      shred[512 + ((4 + wave) * 4 + nf) * 16 + lr];
        partial[(size_t)col * 1024 + blockIdx.x] = ssum;
        partial[(size_t)(256 + col) * 1024 + blockIdx.x] = qsum;
    }
}

// 256 blocks (one per channel) x 256 threads; fixed-order fp64 reduction.
__global__ __launch_bounds__(256) void finalize_stats(const double* __restrict__ partial,
                                                      const float* __restrict__ gamma,
                                                      const float* __restrict__ beta,
                                                      float2* __restrict__ ss,
                                                      int nblocks, double invM) {
    const int c = blockIdx.x;
    const int t = threadIdx.x;
    __shared__ double sh[256];
    __shared__ double sh2[256];
    double s = 0.0, s2 = 0.0;
    for (int b = t; b < nblocks; b += 256) {
        s += partial[(size_t)c * nblocks + b];
        s2 += partial[(size_t)(256 + c) * nblocks + b];
    }
    sh[t] = s;
    sh2[t] = s2;
    __syncthreads();
#pragma unroll
    for (int off = 128; off > 0; off >>= 1) {
        if (t < off) {
            sh[t] += sh[t + off];
            sh2[t] += sh2[t + off];
        }
        __syncthreads();
    }
    if (t == 0) {
        double mu = sh[0] * invM;
        double var = sh2[0] * invM - mu * mu;
        double rstd = 1.0 / sqrt(var + 1e-5);
        double sc = (double)gamma[c] * rstd;
        ss[c] = make_float2((float)sc, (float)((double)beta[c] - mu * sc));
    }
}

// ---------------- Fused BN(affine) + multi-step LIF over T=4 ----------------
__global__ __launch_bounds__(256) void bnlif_bf16(const float* __restrict__ h,
                                                  const float2* __restrict__ ss,
                                                  unsigned short* __restrict__ out,
                                                  int slab4) {
    int t4 = blockIdx.x * 256 + threadIdx.x;
    if (t4 >= slab4) return;
    size_t idx = (size_t)t4 * 4;
    int c0 = (int)(idx & 255);
    float2 p0 = ss[c0], p1 = ss[c0 + 1], p2 = ss[c0 + 2], p3 = ss[c0 + 3];
    size_t slab = (size_t)slab4 * 4;
    float4 v = make_float4(0.f, 0.f, 0.f, 0.f);
#pragma unroll
    for (int t = 0; t < 4; ++t) {
        float4 hv = *(const float4*)(h + (size_t)t * slab + idx);
        float x0 = hv.x * p0.x + p0.y;
        float x1 = hv.y * p1.x + p1.y;
        float x2 = hv.z * p2.x + p2.y;
        float x3 = hv.w * p3.x + p3.y;
        v.x = v.x + (x0 - v.x) * 0.5f;
        v.y = v.y + (x1 - v.y) * 0.5f;
        v.z = v.z + (x2 - v.z) * 0.5f;
        v.w = v.w + (x3 - v.w) * 0.5f;
        ushort4 sp;
        sp.x = (v.x >= 1.0f) ? 0x3F80 : 0;
        sp.y = (v.y >= 1.0f) ? 0x3F80 : 0;
        sp.z = (v.z >= 1.0f) ? 0x3F80 : 0;
        sp.w = (v.w >= 1.0f) ? 0x3F80 : 0;
        v.x = (v.x >= 1.0f) ? 0.0f : v.x;
        v.y = (v.y >= 1.0f) ? 0.0f : v.y;
        v.z = (v.z >= 1.0f) ? 0.0f : v.z;
        v.w = (v.w >= 1.0f) ? 0.0f : v.w;
        *(ushort4*)(out + (size_t)t * slab + idx) = sp;
    }
}

__global__ __launch_bounds__(256) void bnlif_f32(const float* __restrict__ h,
                                                 const float2* __restrict__ ss,
                                                 float* __restrict__ out,
                                                 int slab4) {
    int t4 = blockIdx.x * 256 + threadIdx.x;
    if (t4 >= slab4) return;
    size_t idx = (size_t)t4 * 4;
    int c0 = (int)(idx & 255);
    float2 p0 = ss[c0], p1 = ss[c0 + 1], p2 = ss[c0 + 2], p3 = ss[c0 + 3];
    size_t slab = (size_t)slab4 * 4;
    float4 v = make_float4(0.f, 0.f, 0.f, 0.f);
#pragma unroll
    for (int t = 0; t < 4; ++t) {
        float4 hv = *(const float4*)(h + (size_t)t * slab + idx);
        float x0 = hv.x * p0.x + p0.y;
        float x1 = hv.y * p1.x + p1.y;
        float x2 = hv.z * p2.x + p2.y;
        float x3 = hv.w * p3.x + p3.y;
        v.x = v.x + (x0 - v.x) * 0.5f;
        v.y = v.y + (x1 - v.y) * 0.5f;
        v.z = v.z + (x2 - v.z) * 0.5f;
        v.w = v.w + (x3 - v.w) * 0.5f;
        float4 sp;
        sp.x = (v.x >= 1.0f) ? 1.0f : 0.0f;
        sp.y = (v.y >= 1.0f) ? 1.0f : 0.0f;
        sp.z = (v.z >= 1.0f) ? 1.0f : 0.0f;
        sp.w = (v.w >= 1.0f) ? 1.0f : 0.0f;
        v.x = (v.x >= 1.0f) ? 0.0f : v.x;
        v.y = (v.y >= 1.0f) ? 0.0f : v.y;
        v.z = (v.z >= 1.0f) ? 0.0f : v.z;
        v.w = (v.w >= 1.0f) ? 0.0f : v.w;
        *(float4*)(out + (size_t)t * slab + idx) = sp;
    }
}

extern "C" void kernel_launch(void* const* d_in, const int* in_sizes, int n_in,
                              void* d_out, int out_size, void* d_ws, size_t ws_size,
                              hipStream_t stream) {
    const float* x  = (const float*)d_in[0];
    const float* W1 = (const float*)d_in[1];
    const float* b1 = (const float*)d_in[2];
    const float* g1 = (const float*)d_in[3];
    const float* be1 = (const float*)d_in[4];
    const float* W2 = (const float*)d_in[5];
    const float* b2 = (const float*)d_in[6];
    const float* g2 = (const float*)d_in[7];
    const float* be2 = (const float*)d_in[8];
    float* out = (float*)d_out;

    const int M = in_sizes[0] / 256;            // 131072
    const size_t hBytes = (size_t)M * 256 * 4;  // 128 MiB

    char* ws = (char*)d_ws;
    float* h = (float*)ws;                               // 128 MiB fp32 (h / o)
    unsigned short* s1b = (unsigned short*)(ws + hBytes);        // 64 MiB bf16 spikes
    double* partial = (double*)(ws + hBytes + hBytes / 2);       // 4 MiB
    const int NB = 1024;
    unsigned short* W2catT = (unsigned short*)(ws + hBytes + hBytes / 2 + (size_t)NB * 512 * 8);
    float2* ss1 = (float2*)((char*)W2catT + 3 * 256 * 256 * 2);
    float2* ss2 = ss1 + 256;

    const int slab4 = M * 16;
    const double invM = 1.0 / (double)M;

    dim3 blk(256);

    // W2 -> 3x bf16 split (transposed, n-major)
    split_w2<<<dim3(256), blk, 0, stream>>>(W2, W2catT);

    // ---- layer 1 (fp32 VALU GEMM + fused stats) ----
    sgemm256<<<dim3((M / 128) * 2), blk, 0, stream>>>(x, W1, b1, h, partial);
    finalize_stats<<<dim3(256), blk, 0, stream>>>(partial, g1, be1, ss1, NB, invM);
    bnlif_bf16<<<dim3(slab4 / 256), blk, 0, stream>>>(h, ss1, s1b, slab4);

    // ---- layer 2 (bf16x3 MFMA GEMM, exact; reg-dbuf B; fused stats) ----
    gemm2_mfma<<<dim3(M / 128), dim3(512), 0, stream>>>(s1b, W2catT, b2, h, partial);
    finalize_stats<<<dim3(256), blk, 0, stream>>>(partial, g2, be2, ss2, NB, invM);
    bnlif_f32<<<dim3(slab4 / 256), blk, 0, stream>>>(h, ss2, out, slab4);
}

// Round 7
// 338.433 us; speedup vs baseline: 1.3725x; 1.3725x over previous
//
#include <hip/hip_runtime.h>

// x[T=4,B=32,N=1024,C=256] -> Linear -> BN -> LIF -> Linear -> BN -> LIF
// M = 131072 rows, fp32 in/out.
// GEMM2: spikes are 0/1 (exact bf16) @ exact 3-term bf16 split of W2 (MFMA).
// GEMM1 (round 7): exact-enough 2-term fp16 split of x and W1, 3 products:
//   x = xh + xl*2^-12, W = wh + wl*2^-12 (lo terms stored pre-scaled by 2^12)
//   h = (xh@wh) + [(xh@wl') + (xl'@wh)]*2^-12   (lo*lo ~2^-24 rel, dropped)
// All products exact in fp32; accumulation fp32 (MFMA) -> error ~ fp32 reorder.

typedef __attribute__((ext_vector_type(8))) short bf16x8;
typedef __attribute__((ext_vector_type(8))) _Float16 f16x8;
typedef __attribute__((ext_vector_type(4))) _Float16 f16x4;
typedef __attribute__((ext_vector_type(4))) float f32x4;

__device__ __forceinline__ unsigned short f32_to_bf16_rne(float f) {
    unsigned int u = __builtin_bit_cast(unsigned int, f);
    u += 0x7FFFu + ((u >> 16) & 1u);
    return (unsigned short)(u >> 16);
}
__device__ __forceinline__ float bf16_to_f32(unsigned short h) {
    unsigned int u = ((unsigned int)h) << 16;
    return __builtin_bit_cast(float, u);
}

// -------- W1 split: W1[k][n] fp32 -> W1hiT/W1loT[n][k] fp16 (lo pre-scaled 2^12) -----
__global__ __launch_bounds__(256) void split_w1(const float* __restrict__ W1,
                                                _Float16* __restrict__ BhiT,
                                                _Float16* __restrict__ BloT) {
    int i = blockIdx.x * 256 + threadIdx.x;  // 65536
    int k = i >> 8, n = i & 255;
    float w = W1[i];
    _Float16 hi = (_Float16)w;
    _Float16 lo = (_Float16)((w - (float)hi) * 4096.0f);
    BhiT[(size_t)n * 256 + k] = hi;
    BloT[(size_t)n * 256 + k] = lo;
}

// -------- W2 split: W2[k][n] fp32 -> W2catT[t][n][k] bf16, t=hi/mid/lo (exact sum) ----
__global__ __launch_bounds__(256) void split_w2(const float* __restrict__ W2,
                                                unsigned short* __restrict__ Bt) {
    int i = blockIdx.x * 256 + threadIdx.x;  // 65536
    int k = i >> 8, n = i & 255;
    float w = W2[i];
    unsigned short hi = f32_to_bf16_rne(w);
    float r = w - bf16_to_f32(hi);
    unsigned short mid = f32_to_bf16_rne(r);
    float r2 = r - bf16_to_f32(mid);
    unsigned short lo = f32_to_bf16_rne(r2);
    Bt[(size_t)(0 * 256 + n) * 256 + k] = hi;
    Bt[(size_t)(1 * 256 + n) * 256 + k] = mid;
    Bt[(size_t)(2 * 256 + n) * 256 + k] = lo;
}

// ---------------- GEMM1 (MFMA, fp16 2-split x 3 products) ---------------------------
// 512 thr / 8 waves; A tile fp32 -> 2 fp16 LDS tiles (hi, lo*2^12), 128 KB, XOR-
// swizzled; barrier-free K-loop; B frags register-double-buffered (full-k0 distance).
// Fused column stats in epilogue.
__global__ __launch_bounds__(512) void gemm1_mfma(const float* __restrict__ A,
                                                  const _Float16* __restrict__ Bhi,
                                                  const _Float16* __restrict__ Blo,
                                                  const float* __restrict__ bias,
                                                  float* __restrict__ C,
                                                  double* __restrict__ partial) {
    __shared__ __align__(16) _Float16 Ahi[128 * 256];  // 64 KB
    __shared__ __align__(16) _Float16 Alo[128 * 256];  // 64 KB
    const size_t m0 = (size_t)blockIdx.x * 128;
    const int tid = threadIdx.x;
    const int lane = tid & 63;
    const int wave = tid >> 6;   // 0..7
    const int wr = wave >> 2;    // 0..1
    const int wc = wave & 3;     // 0..3
    const int lrow = lane & 15, lchunk = lane >> 4;

    const _Float16* BhiB = Bhi + ((size_t)(64 * wc + lrow)) * 256 + lchunk * 8;
    const _Float16* BloB = Blo + ((size_t)(64 * wc + lrow)) * 256 + lchunk * 8;

    f16x8 bh[2][4], bl[2][4];
#define LOADB1(buf, kk)                                                   \
    _Pragma("unroll") for (int nf = 0; nf < 4; ++nf) {                    \
        bh[buf][nf] = *(const f16x8*)(BhiB + nf * 4096 + (kk) * 32);      \
        bl[buf][nf] = *(const f16x8*)(BloB + nf * 4096 + (kk) * 32);      \
    }

    LOADB1(0, 0)  // in flight during staging

    // ---- stage A tile: fp32 global -> (hi, lo*4096) fp16 LDS, swizzled ----
    {
        const float* src = A + m0 * 256;
#pragma unroll
        for (int it = 0; it < 16; ++it) {
            unsigned i4 = (unsigned)(it * 512 + tid);   // float4 index, 8192 total
            float4 v = *(const float4*)(src + (size_t)i4 * 4);
            float f[4] = {v.x, v.y, v.z, v.w};
            f16x4 hi4, lo4;
#pragma unroll
            for (int e = 0; e < 4; ++e) {
                _Float16 hh = (_Float16)f[e];
                hi4[e] = hh;
                lo4[e] = (_Float16)((f[e] - (float)hh) * 4096.0f);
            }
            unsigned off = i4 * 8u;                     // byte offset in f16 tile
            unsigned swz = off ^ (((off >> 9) & 7u) << 4);
            *(f16x4*)((char*)Ahi + swz) = hi4;
            *(f16x4*)((char*)Alo + swz) = lo4;
        }
    }
    __syncthreads();

    f32x4 acc0[4][4] = {}, acc1[4][4] = {};

#pragma unroll
    for (int k0 = 0; k0 < 8; ++k0) {
        const int cur = k0 & 1;
        if (k0 < 7) { LOADB1(cur ^ 1, k0 + 1) }
        f16x8 ah[4], al[4];
#pragma unroll
        for (int mf = 0; mf < 4; ++mf) {
            unsigned r = (unsigned)(64 * wr + 16 * mf + lrow);
            unsigned off = (r * 512u + (unsigned)(k0 * 64 + lchunk * 16)) ^ ((r & 7u) << 4);
            ah[mf] = *(const f16x8*)((const char*)Ahi + off);
            al[mf] = *(const f16x8*)((const char*)Alo + off);
        }
#pragma unroll
        for (int nf = 0; nf < 4; ++nf)
#pragma unroll
            for (int mf = 0; mf < 4; ++mf)
                acc0[mf][nf] = __builtin_amdgcn_mfma_f32_16x16x32_f16(
                    ah[mf], bh[cur][nf], acc0[mf][nf], 0, 0, 0);
#pragma unroll
        for (int nf = 0; nf < 4; ++nf)
#pragma unroll
            for (int mf = 0; mf < 4; ++mf)
                acc1[mf][nf] = __builtin_amdgcn_mfma_f32_16x16x32_f16(
                    ah[mf], bl[cur][nf], acc1[mf][nf], 0, 0, 0);
#pragma unroll
        for (int nf = 0; nf < 4; ++nf)
#pragma unroll
            for (int mf = 0; mf < 4; ++mf)
                acc1[mf][nf] = __builtin_amdgcn_mfma_f32_16x16x32_f16(
                    al[mf], bh[cur][nf], acc1[mf][nf], 0, 0, 0);
    }
#undef LOADB1

    // ---- C write (h = acc0 + acc1*2^-12 + bias) + lane-local fp64 column sums ----
    const float UNSCALE = 1.0f / 4096.0f;
    double s[4], q[4];
#pragma unroll
    for (int nf = 0; nf < 4; ++nf) {
        int col = 64 * wc + 16 * nf + lrow;
        float bvv = bias[col];
        double ss = 0.0, qq = 0.0;
#pragma unroll
        for (int mf = 0; mf < 4; ++mf) {
            size_t rowb = m0 + 64 * wr + 16 * mf + 4 * lchunk;
#pragma unroll
            for (int e = 0; e < 4; ++e) {
                float hv = acc0[mf][nf][e] + acc1[mf][nf][e] * UNSCALE + bvv;
                C[(rowb + e) * 256 + col] = hv;
                ss += (double)hv;
                qq += (double)hv * (double)hv;
            }
        }
        s[nf] = ss;
        q[nf] = qq;
    }
#pragma unroll
    for (int nf = 0; nf < 4; ++nf) {
        s[nf] += __shfl_xor(s[nf], 16);
        s[nf] += __shfl_xor(s[nf], 32);
        q[nf] += __shfl_xor(q[nf], 16);
        q[nf] += __shfl_xor(q[nf], 32);
    }
    __syncthreads();
    double* shred = (double*)Ahi;
    if (lane < 16) {
#pragma unroll
        for (int nf = 0; nf < 4; ++nf) {
            shred[(wave * 4 + nf) * 16 + lane] = s[nf];
            shred[512 + (wave * 4 + nf) * 16 + lane] = q[nf];
        }
    }
    __syncthreads();
    if (wave < 4) {
        int nf = lane >> 4, lr = lane & 15;
        int col = 64 * wave + 16 * nf + lr;
        double ssum = shred[(wave * 4 + nf) * 16 + lr] +
                      shred[((4 + wave) * 4 + nf) * 16 + lr];
        double qsum = shred[512 + (wave * 4 + nf) * 16 + lr] +
                      shred[512 + ((4 + wave) * 4 + nf) * 16 + lr];
        partial[(size_t)col * 1024 + blockIdx.x] = ssum;
        partial[(size_t)(256 + col) * 1024 + blockIdx.x] = qsum;
    }
}

// ---------------- GEMM2 (MFMA): C = spikes_bf16 @ (Whi+Wmid+Wlo) + bias --------------
// Round-5 config: bb[2][12] full-k0-distance prefetch; A tile 64KB staged once,
// XOR-swizzled; barrier-free K-loop; fused stats.
__global__ __launch_bounds__(512) void gemm2_mfma(const unsigned short* __restrict__ A,
                                                  const unsigned short* __restrict__ Bt,
                                                  const float* __restrict__ bias,
                                                  float* __restrict__ C,
                                                  double* __restrict__ partial) {
    __shared__ __align__(16) unsigned short Asw[128 * 256];  // 64 KB
    const size_t m0 = (size_t)blockIdx.x * 128;
    const int tid = threadIdx.x;
    const int lane = tid & 63;
    const int wave = tid >> 6;   // 0..7
    const int wr = wave >> 2;    // 0..1
    const int wc = wave & 3;     // 0..3
    const int lrow = lane & 15, lchunk = lane >> 4;

    // ---- stage contiguous 64KB A tile; linear global reads, swizzled LDS writes ----
    {
        const char* src = (const char*)(A + m0 * 256);
        char* dst = (char*)Asw;
#pragma unroll
        for (int it = 0; it < 8; ++it) {
            unsigned off = (unsigned)(it * 512 + tid) * 16u;
            float4 v = *(const float4*)(src + off);
            unsigned swz = off ^ (((off >> 9) & 7u) << 4);
            *(float4*)(dst + swz) = v;
        }
    }

    const unsigned short* Bbase =
        Bt + ((size_t)(64 * wc + lrow)) * 256 + lchunk * 8;

    bf16x8 bb[2][12];
#define LOADB(buf, kk)                                                        \
    _Pragma("unroll") for (int t = 0; t < 3; ++t)                             \
    _Pragma("unroll") for (int nf = 0; nf < 4; ++nf)                          \
        bb[buf][t * 4 + nf] = *(const bf16x8*)(Bbase + (size_t)t * 65536 +    \
                                               nf * 4096 + (kk) * 32);

    LOADB(0, 0)
    __syncthreads();

    f32x4 acc[4][4] = {};

#pragma unroll
    for (int k0 = 0; k0 < 8; ++k0) {
        const int cur = k0 & 1;
        if (k0 < 7) { LOADB(cur ^ 1, k0 + 1) }
        bf16x8 af[4];
#pragma unroll
        for (int mf = 0; mf < 4; ++mf) {
            unsigned r = (unsigned)(64 * wr + 16 * mf + lrow);
            unsigned off = r * 512u + (unsigned)(k0 * 64 + lchunk * 16);
            off ^= ((r & 7u) << 4);
            af[mf] = *(const bf16x8*)((const char*)Asw + off);
        }
#pragma unroll
        for (int t = 0; t < 3; ++t)
#pragma unroll
            for (int nf = 0; nf < 4; ++nf)
#pragma unroll
                for (int mf = 0; mf < 4; ++mf)
                    acc[mf][nf] = __builtin_amdgcn_mfma_f32_16x16x32_bf16(
                        af[mf], bb[cur][t * 4 + nf], acc[mf][nf], 0, 0, 0);
    }
#undef LOADB

    // ---- C write + lane-local fp64 column sums ----
    double s[4], q[4];
#pragma unroll
    for (int nf = 0; nf < 4; ++nf) {
        int col = 64 * wc + 16 * nf + lrow;
        float bvv = bias[col];
        double ss = 0.0, qq = 0.0;
#pragma unroll
        for (int mf = 0; mf < 4; ++mf) {
            size_t rowb = m0 + 64 * wr + 16 * mf + 4 * lchunk;
#pragma unroll
            for (int e = 0; e < 4; ++e) {
                float hv = acc[mf][nf][e] + bvv;
                C[(rowb + e) * 256 + col] = hv;
                ss += (double)hv;
                qq += (double)hv * (double)hv;
            }
        }
        s[nf] = ss;
        q[nf] = qq;
    }
#pragma unroll
    for (int nf = 0; nf < 4; ++nf) {
        s[nf] += __shfl_xor(s[nf], 16);
        s[nf] += __shfl_xor(s[nf], 32);
        q[nf] += __shfl_xor(q[nf], 16);
        q[nf] += __shfl_xor(q[nf], 32);
    }
    __syncthreads();
    double* shred = (double*)Asw;
    if (lane < 16) {
#pragma unroll
        for (int nf = 0; nf < 4; ++nf) {
            shred[(wave * 4 + nf) * 16 + lane] = s[nf];
            shred[512 + (wave * 4 + nf) * 16 + lane] = q[nf];
        }
    }
    __syncthreads();
    if (wave < 4) {
        int nf = lane >> 4, lr = lane & 15;
        int col = 64 * wave + 16 * nf + lr;
        double ssum = shred[(wave * 4 + nf) * 16 + lr] +
                      shred[((4 + wave) * 4 + nf) * 16 + lr];
        double qsum = shred[512 + (wave * 4 + nf) * 16 + lr] +
                      shred[512 + ((4 + wave) * 4 + nf) * 16 + lr];
        partial[(size_t)col * 1024 + blockIdx.x] = ssum;
        partial[(size_t)(256 + col) * 1024 + blockIdx.x] = qsum;
    }
}

// 256 blocks (one per channel) x 256 threads; fixed-order fp64 reduction.
__global__ __launch_bounds__(256) void finalize_stats(const double* __restrict__ partial,
                                                      const float* __restrict__ gamma,
                                                      const float* __restrict__ beta,
                                                      float2* __restrict__ ss,
                                                      int nblocks, double invM) {
    const int c = blockIdx.x;
    const int t = threadIdx.x;
    __shared__ double sh[256];
    __shared__ double sh2[256];
    double s = 0.0, s2 = 0.0;
    for (int b = t; b < nblocks; b += 256) {
        s += partial[(size_t)c * nblocks + b];
        s2 += partial[(size_t)(256 + c) * nblocks + b];
    }
    sh[t] = s;
    sh2[t] = s2;
    __syncthreads();
#pragma unroll
    for (int off = 128; off > 0; off >>= 1) {
        if (t < off) {
            sh[t] += sh[t + off];
            sh2[t] += sh2[t + off];
        }
        __syncthreads();
    }
    if (t == 0) {
        double mu = sh[0] * invM;
        double var = sh2[0] * invM - mu * mu;
        double rstd = 1.0 / sqrt(var + 1e-5);
        double sc = (double)gamma[c] * rstd;
        ss[c] = make_float2((float)sc, (float)((double)beta[c] - mu * sc));
    }
}

// ---------------- Fused BN(affine) + multi-step LIF over T=4 ----------------
__global__ __launch_bounds__(256) void bnlif_bf16(const float* __restrict__ h,
                                                  const float2* __restrict__ ss,
                                                  unsigned short* __restrict__ out,
                                                  int slab4) {
    int t4 = blockIdx.x * 256 + threadIdx.x;
    if (t4 >= slab4) return;
    size_t idx = (size_t)t4 * 4;
    int c0 = (int)(idx & 255);
    float2 p0 = ss[c0], p1 = ss[c0 + 1], p2 = ss[c0 + 2], p3 = ss[c0 + 3];
    size_t slab = (size_t)slab4 * 4;
    float4 v = make_float4(0.f, 0.f, 0.f, 0.f);
#pragma unroll
    for (int t = 0; t < 4; ++t) {
        float4 hv = *(const float4*)(h + (size_t)t * slab + idx);
        float x0 = hv.x * p0.x + p0.y;
        float x1 = hv.y * p1.x + p1.y;
        float x2 = hv.z * p2.x + p2.y;
        float x3 = hv.w * p3.x + p3.y;
        v.x = v.x + (x0 - v.x) * 0.5f;
        v.y = v.y + (x1 - v.y) * 0.5f;
        v.z = v.z + (x2 - v.z) * 0.5f;
        v.w = v.w + (x3 - v.w) * 0.5f;
        ushort4 sp;
        sp.x = (v.x >= 1.0f) ? 0x3F80 : 0;
        sp.y = (v.y >= 1.0f) ? 0x3F80 : 0;
        sp.z = (v.z >= 1.0f) ? 0x3F80 : 0;
        sp.w = (v.w >= 1.0f) ? 0x3F80 : 0;
        v.x = (v.x >= 1.0f) ? 0.0f : v.x;
        v.y = (v.y >= 1.0f) ? 0.0f : v.y;
        v.z = (v.z >= 1.0f) ? 0.0f : v.z;
        v.w = (v.w >= 1.0f) ? 0.0f : v.w;
        *(ushort4*)(out + (size_t)t * slab + idx) = sp;
    }
}

__global__ __launch_bounds__(256) void bnlif_f32(const float* __restrict__ h,
                                                 const float2* __restrict__ ss,
                                                 float* __restrict__ out,
                                                 int slab4) {
    int t4 = blockIdx.x * 256 + threadIdx.x;
    if (t4 >= slab4) return;
    size_t idx = (size_t)t4 * 4;
    int c0 = (int)(idx & 255);
    float2 p0 = ss[c0], p1 = ss[c0 + 1], p2 = ss[c0 + 2], p3 = ss[c0 + 3];
    size_t slab = (size_t)slab4 * 4;
    float4 v = make_float4(0.f, 0.f, 0.f, 0.f);
#pragma unroll
    for (int t = 0; t < 4; ++t) {
        float4 hv = *(const float4*)(h + (size_t)t * slab + idx);
        float x0 = hv.x * p0.x + p0.y;
        float x1 = hv.y * p1.x + p1.y;
        float x2 = hv.z * p2.x + p2.y;
        float x3 = hv.w * p3.x + p3.y;
        v.x = v.x + (x0 - v.x) * 0.5f;
        v.y = v.y + (x1 - v.y) * 0.5f;
        v.z = v.z + (x2 - v.z) * 0.5f;
        v.w = v.w + (x3 - v.w) * 0.5f;
        float4 sp;
        sp.x = (v.x >= 1.0f) ? 1.0f : 0.0f;
        sp.y = (v.y >= 1.0f) ? 1.0f : 0.0f;
        sp.z = (v.z >= 1.0f) ? 1.0f : 0.0f;
        sp.w = (v.w >= 1.0f) ? 1.0f : 0.0f;
        v.x = (v.x >= 1.0f) ? 0.0f : v.x;
        v.y = (v.y >= 1.0f) ? 0.0f : v.y;
        v.z = (v.z >= 1.0f) ? 0.0f : v.z;
        v.w = (v.w >= 1.0f) ? 0.0f : v.w;
        *(float4*)(out + (size_t)t * slab + idx) = sp;
    }
}

extern "C" void kernel_launch(void* const* d_in, const int* in_sizes, int n_in,
                              void* d_out, int out_size, void* d_ws, size_t ws_size,
                              hipStream_t stream) {
    const float* x  = (const float*)d_in[0];
    const float* W1 = (const float*)d_in[1];
    const float* b1 = (const float*)d_in[2];
    const float* g1 = (const float*)d_in[3];
    const float* be1 = (const float*)d_in[4];
    const float* W2 = (const float*)d_in[5];
    const float* b2 = (const float*)d_in[6];
    const float* g2 = (const float*)d_in[7];
    const float* be2 = (const float*)d_in[8];
    float* out = (float*)d_out;

    const int M = in_sizes[0] / 256;            // 131072
    const size_t hBytes = (size_t)M * 256 * 4;  // 128 MiB

    char* ws = (char*)d_ws;
    float* h = (float*)ws;                                   // 128 MiB fp32 (h / o)
    unsigned short* s1b = (unsigned short*)(ws + hBytes);    // 64 MiB bf16 spikes
    double* partial = (double*)(ws + hBytes + hBytes / 2);   // 4 MiB
    const int NB = 1024;
    unsigned short* W2catT = (unsigned short*)(ws + hBytes + hBytes / 2 + (size_t)NB * 512 * 8);
    float2* ss1 = (float2*)((char*)W2catT + 3 * 256 * 256 * 2);
    float2* ss2 = ss1 + 256;
    _Float16* W1hiT = (_Float16*)(ss2 + 256);
    _Float16* W1loT = W1hiT + 256 * 256;

    const int slab4 = M * 16;
    const double invM = 1.0 / (double)M;

    dim3 blk(256);

    // weight splits
    split_w1<<<dim3(256), blk, 0, stream>>>(W1, W1hiT, W1loT);
    split_w2<<<dim3(256), blk, 0, stream>>>(W2, W2catT);

    // ---- layer 1 (fp16x2-split MFMA GEMM + fused stats) ----
    gemm1_mfma<<<dim3(M / 128), dim3(512), 0, stream>>>(x, W1hiT, W1loT, b1, h, partial);
    finalize_stats<<<dim3(256), blk, 0, stream>>>(partial, g1, be1, ss1, NB, invM);
    bnlif_bf16<<<dim3(slab4 / 256), blk, 0, stream>>>(h, ss1, s1b, slab4);

    // ---- layer 2 (bf16x3 MFMA GEMM, exact; reg-dbuf B; fused stats) ----
    gemm2_mfma<<<dim3(M / 128), dim3(512), 0, stream>>>(s1b, W2catT, b2, h, partial);
    finalize_stats<<<dim3(256), blk, 0, stream>>>(partial, g2, be2, ss2, NB, invM);
    bnlif_f32<<<dim3(slab4 / 256), blk, 0, stream>>>(h, ss2, out, slab4);
}